// Round 12
// baseline (126.756 us; speedup 1.0000x reference)
//
#include <hip/hip_runtime.h>

#define IN_F 128
#define HRH 4            // hist node-ranges (LDS 50KB)
#define HCD 64           // dst chunks (= bin chunks, chunkoff table)
#define HCS 32           // src chunks (degree count only)
#define HRB 8            // bin node-ranges (LDS cursor 25KB)
#define HIST_RS 12544    // >= ceil(nN/HRH) for nN=50000
#define BIN_RS 6272      // >= ceil(nN/HRB)
#define LROW 68          // LDS tile row stride in uints (272B: conflict-free A-frag reads)

typedef __attribute__((ext_vector_type(8))) short bf16x8;
typedef __attribute__((ext_vector_type(4))) float f32x4;

static __device__ __forceinline__ unsigned short f2bf(float x) {
    unsigned u = __float_as_uint(x);
    unsigned r = (u + 0x7FFFu + ((u >> 16) & 1u)) >> 16;
    return (unsigned short)r;
}

#define RFL(x) __builtin_amdgcn_readfirstlane(x)

// ---------------- privatized histograms: dst (64 chunks) + src (32 chunks) ----
__global__ __launch_bounds__(256) void k_hist(const int* __restrict__ src,
                                              const int* __restrict__ dst,
                                              int* __restrict__ dstpart,
                                              int* __restrict__ srcpart,
                                              int nN, int nE) {
    __shared__ int h[HIST_RS];
    int bid = blockIdx.x;
    const int* key;
    int* part;
    int r, c, nch;
    if (bid < HRH * HCD) {
        key = dst; part = dstpart; nch = HCD;
        r = bid / HCD; c = bid % HCD;
    } else {
        bid -= HRH * HCD;
        key = src; part = srcpart; nch = HCS;
        r = bid / HCS; c = bid % HCS;
    }
    const int rs   = (nN + HRH - 1) / HRH;
    const int rbeg = r * rs;
    const int rsize = min(rs, nN - rbeg);
    if (rsize <= 0) return;

    for (int i = threadIdx.x; i < rsize; i += 256) h[i] = 0;
    __syncthreads();

    const int chunk = (nE + nch - 1) / nch;
    const int ebeg = c * chunk;
    const int eend = min(ebeg + chunk, nE);

    if ((ebeg & 3) == 0) {
        for (int i = ebeg + threadIdx.x * 4; i < eend; i += 256 * 4) {
            if (i + 3 < eend) {
                const int4 k4 = *reinterpret_cast<const int4*>(key + i);
                int a;
                a = k4.x - rbeg; if ((unsigned)a < (unsigned)rsize) atomicAdd(&h[a], 1);
                a = k4.y - rbeg; if ((unsigned)a < (unsigned)rsize) atomicAdd(&h[a], 1);
                a = k4.z - rbeg; if ((unsigned)a < (unsigned)rsize) atomicAdd(&h[a], 1);
                a = k4.w - rbeg; if ((unsigned)a < (unsigned)rsize) atomicAdd(&h[a], 1);
            } else {
                for (int j = i; j < eend; ++j) {
                    int a = key[j] - rbeg;
                    if ((unsigned)a < (unsigned)rsize) atomicAdd(&h[a], 1);
                }
            }
        }
    } else {
        for (int i = ebeg + threadIdx.x; i < eend; i += 256) {
            int a = key[i] - rbeg;
            if ((unsigned)a < (unsigned)rsize) atomicAdd(&h[a], 1);
        }
    }
    __syncthreads();

    int* pout = part + (size_t)c * nN + rbeg;
    for (int i = threadIdx.x; i < rsize; i += 256) pout[i] = h[i];
}

// ---------------- merge: src sums -> dinv_out; dst partials -> per-chunk prefixes
__global__ void k_merge(int* __restrict__ dstpart, const int* __restrict__ srcpart,
                        int* __restrict__ cnt_pad, int* __restrict__ creal,
                        float* __restrict__ dinv_out, float* __restrict__ dinv_in,
                        int nN) {
    const int n = blockIdx.x * blockDim.x + threadIdx.x;
    if (n > nN) return;
    if (n == nN) { cnt_pad[n] = 0; return; }   // scan sentinel slot
    int s = 0;
#pragma unroll 4
    for (int c = 0; c < HCS; ++c) s += srcpart[(size_t)c * nN + n];
    int run = 0;
#pragma unroll 4
    for (int c = 0; c < HCD; ++c) {
        const size_t idx = (size_t)c * nN + n;
        int v = dstpart[idx];
        dstpart[idx] = run;
        run += v;
    }
    cnt_pad[n]  = (run + 7) & ~7;
    creal[n]    = run;
    dinv_out[n] = rsqrtf(fmaxf((float)s, 1.0f));
    dinv_in[n]  = rsqrtf(fmaxf((float)run, 1.0f));
}

// ---------------- hierarchical exclusive scan over nNs = nN+1 elements -------
__global__ __launch_bounds__(256) void k_scan_blk(const int* __restrict__ cnt,
                                                  int* __restrict__ offs,
                                                  int* __restrict__ part, int nNs) {
    __shared__ int ts[256];
    const int t = threadIdx.x;
    const int base = blockIdx.x * 1024 + t * 4;
    int4 v = make_int4(0, 0, 0, 0);
    if (base + 3 < nNs) {
        v = *reinterpret_cast<const int4*>(cnt + base);
    } else {
        if (base + 0 < nNs) v.x = cnt[base + 0];
        if (base + 1 < nNs) v.y = cnt[base + 1];
        if (base + 2 < nNs) v.z = cnt[base + 2];
        if (base + 3 < nNs) v.w = cnt[base + 3];
    }
    const int s = v.x + v.y + v.z + v.w;
    ts[t] = s;
    __syncthreads();
    for (int d = 1; d < 256; d <<= 1) {
        int u = (t >= d) ? ts[t - d] : 0;
        __syncthreads();
        ts[t] += u;
        __syncthreads();
    }
    const int ex = ts[t] - s;
    if (t == 255) part[blockIdx.x] = ts[255];
    int4 o;
    o.x = ex;
    o.y = o.x + v.x;
    o.z = o.y + v.y;
    o.w = o.z + v.z;
    if (base + 3 < nNs) {
        *reinterpret_cast<int4*>(offs + base) = o;
    } else {
        if (base + 0 < nNs) offs[base + 0] = o.x;
        if (base + 1 < nNs) offs[base + 1] = o.y;
        if (base + 2 < nNs) offs[base + 2] = o.z;
        if (base + 3 < nNs) offs[base + 3] = o.w;
    }
}

__global__ __launch_bounds__(256) void k_scan_top(int* __restrict__ part, int nb) {
    __shared__ int ts[256];
    const int t = threadIdx.x;
    const int v = (t < nb) ? part[t] : 0;
    ts[t] = v;
    __syncthreads();
    for (int d = 1; d < 256; d <<= 1) {
        int u = (t >= d) ? ts[t - d] : 0;
        __syncthreads();
        ts[t] += u;
        __syncthreads();
    }
    if (t < nb) part[t] = ts[t] - v;
}

__global__ __launch_bounds__(256) void k_scan_add(int* __restrict__ offs,
                                                  const int* __restrict__ part,
                                                  int nNs) {
    const int base = blockIdx.x * 1024 + threadIdx.x * 4;
    const int add = part[blockIdx.x];
    if (base + 3 < nNs) {
        int4 o = *reinterpret_cast<int4*>(offs + base);
        o.x += add; o.y += add; o.z += add; o.w += add;
        *reinterpret_cast<int4*>(offs + base) = o;
    } else {
#pragma unroll
        for (int j = 0; j < 4; ++j)
            if (base + j < nNs) offs[base + j] += add;
    }
}

// ---------------- fill pad slots with the zero-row index nN ----------------
__global__ void k_pad(const int* __restrict__ offs, const int* __restrict__ creal,
                      int* __restrict__ eidx, int nN) {
    const int n = blockIdx.x * blockDim.x + threadIdx.x;
    if (n >= nN) return;
    const int s = offs[n] + creal[n];
    const int e = offs[n + 1];
    for (int i = s; i < e; ++i) eidx[i] = nN;
}

// ---------------- bucket edges by dst via LDS cursors (no global atomics) ----
__global__ __launch_bounds__(256) void k_bin2(const int* __restrict__ src,
                                              const int* __restrict__ dst,
                                              const int* __restrict__ offs,
                                              const int* __restrict__ chunkoff,
                                              int* __restrict__ eidx, int nN, int nE) {
    __shared__ int cur[BIN_RS];
    const int bid = blockIdx.x;
    const int r = bid / HCD;
    const int c = bid % HCD;
    const int rs = (nN + HRB - 1) / HRB;
    const int rbeg = r * rs;
    const int rsize = min(rs, nN - rbeg);
    if (rsize <= 0) return;

    for (int i = threadIdx.x; i < rsize; i += 256)
        cur[i] = offs[rbeg + i] + chunkoff[(size_t)c * nN + rbeg + i];
    __syncthreads();

    const int chunk = (nE + HCD - 1) / HCD;
    const int ebeg = c * chunk;
    const int eend = min(ebeg + chunk, nE);
    for (int i = ebeg + threadIdx.x * 4; i < eend; i += 256 * 4) {
        if (i + 3 < eend) {
            const int4 d4 = *reinterpret_cast<const int4*>(dst + i);
            int d;
            d = d4.x - rbeg; if ((unsigned)d < (unsigned)rsize) { int p = atomicAdd(&cur[d], 1); eidx[p] = src[i + 0]; }
            d = d4.y - rbeg; if ((unsigned)d < (unsigned)rsize) { int p = atomicAdd(&cur[d], 1); eidx[p] = src[i + 1]; }
            d = d4.z - rbeg; if ((unsigned)d < (unsigned)rsize) { int p = atomicAdd(&cur[d], 1); eidx[p] = src[i + 2]; }
            d = d4.w - rbeg; if ((unsigned)d < (unsigned)rsize) { int p = atomicAdd(&cur[d], 1); eidx[p] = src[i + 3]; }
        } else {
            for (int j = i; j < eend; ++j) {
                int d = dst[j] - rbeg;
                if ((unsigned)d < (unsigned)rsize) { int p = atomicAdd(&cur[d], 1); eidx[p] = src[j]; }
            }
        }
    }
}

// ---------------- h[n] = bf16(feat[n] * dinv_out[n]); row nN = zeros ----------
__global__ __launch_bounds__(256) void k_scale(const float* __restrict__ feat,
                                               const float* __restrict__ dinv,
                                               unsigned short* __restrict__ h, int nN) {
    const int i = blockIdx.x * 256 + threadIdx.x;  // one thread = 4 elems
    if (i >= (nN + 1) * (IN_F / 4)) return;
    const int node = i >> 5;
    const int j = (i & 31) * 4;
    ushort4 o = make_ushort4(0, 0, 0, 0);
    if (node < nN) {
        const float s = dinv[node];
        const float4 v = *reinterpret_cast<const float4*>(feat + (size_t)node * IN_F + j);
        o.x = f2bf(v.x * s);
        o.y = f2bf(v.y * s);
        o.z = f2bf(v.z * s);
        o.w = f2bf(v.w * s);
    }
    *reinterpret_cast<ushort4*>(h + (size_t)node * IN_F + j) = o;
}

// ---------------- Wt[j][k] = bf16(W[k][j]) (single block) ----------------
__global__ __launch_bounds__(256) void k_wprep(const float* __restrict__ W,
                                               unsigned short* __restrict__ wt) {
    __shared__ float wl[128 * 128];
    for (int i = threadIdx.x * 4; i < 128 * 128; i += 256 * 4)
        *reinterpret_cast<float4*>(&wl[i]) = *reinterpret_cast<const float4*>(&W[i]);
    __syncthreads();
    const int col = threadIdx.x >> 1;
    const int k0  = (threadIdx.x & 1) * 64;
    for (int k = k0; k < k0 + 64; ++k)
        wt[col * 128 + k] = f2bf(wl[k * 128 + col]);
}

// ---------------- fused gather + GEMM: 4-row scalar-index interleaved gather --
// All 4 rows of a wave gathered CONCURRENTLY with scalar (SMEM/SALU) index
// path: 32 scattered h-loads in flight per wave, idx batches prefetched while
// h-loads fly. Bins padded to x8 -> batches never cross rows.
#define ISSUE8(vv, a0, a1)                                                        \
    vv##0 = *reinterpret_cast<const unsigned*>(h + (size_t)RFL(a0.x) * IN_F + lo); \
    vv##1 = *reinterpret_cast<const unsigned*>(h + (size_t)RFL(a0.y) * IN_F + lo); \
    vv##2 = *reinterpret_cast<const unsigned*>(h + (size_t)RFL(a0.z) * IN_F + lo); \
    vv##3 = *reinterpret_cast<const unsigned*>(h + (size_t)RFL(a0.w) * IN_F + lo); \
    vv##4 = *reinterpret_cast<const unsigned*>(h + (size_t)RFL(a1.x) * IN_F + lo); \
    vv##5 = *reinterpret_cast<const unsigned*>(h + (size_t)RFL(a1.y) * IN_F + lo); \
    vv##6 = *reinterpret_cast<const unsigned*>(h + (size_t)RFL(a1.z) * IN_F + lo); \
    vv##7 = *reinterpret_cast<const unsigned*>(h + (size_t)RFL(a1.w) * IN_F + lo);

#define ACC8(vv, ax, ay)                                                            \
    ax += __uint_as_float(vv##0 << 16); ay += __uint_as_float(vv##0 & 0xFFFF0000u); \
    ax += __uint_as_float(vv##1 << 16); ay += __uint_as_float(vv##1 & 0xFFFF0000u); \
    ax += __uint_as_float(vv##2 << 16); ay += __uint_as_float(vv##2 & 0xFFFF0000u); \
    ax += __uint_as_float(vv##3 << 16); ay += __uint_as_float(vv##3 & 0xFFFF0000u); \
    ax += __uint_as_float(vv##4 << 16); ay += __uint_as_float(vv##4 & 0xFFFF0000u); \
    ax += __uint_as_float(vv##5 << 16); ay += __uint_as_float(vv##5 & 0xFFFF0000u); \
    ax += __uint_as_float(vv##6 << 16); ay += __uint_as_float(vv##6 & 0xFFFF0000u); \
    ax += __uint_as_float(vv##7 << 16); ay += __uint_as_float(vv##7 & 0xFFFF0000u);

#define PREF(i, e, p0, p1)                                                     \
    if (i + 8 < e) { p0 = *reinterpret_cast<const int4*>(eidx + RFL(i) + 8);   \
                     p1 = *reinterpret_cast<const int4*>(eidx + RFL(i) + 12); }

__global__ __launch_bounds__(256) void k_gg(
    const unsigned short* __restrict__ h, const int* __restrict__ eidx,
    const int* __restrict__ offs, const unsigned short* __restrict__ wt,
    const float* __restrict__ bias, const float* __restrict__ dinv_in,
    float* __restrict__ out, int nN) {
    __shared__ unsigned tile[16 * LROW];
    const int lane = threadIdx.x & 63;
    const int wave = threadIdx.x >> 6;
    const int blk16 = blockIdx.x * 16;
    const size_t lo = (size_t)(lane * 2);
    const int nbase = blk16 + wave * 4;

    int begA = 0, endA = 0, begB = 0, endB = 0, begC = 0, endC = 0, begD = 0, endD = 0;
    if (nbase + 0 < nN) { begA = RFL(offs[nbase + 0]); endA = RFL(offs[nbase + 1]); }
    if (nbase + 1 < nN) { begB = RFL(offs[nbase + 1]); endB = RFL(offs[nbase + 2]); }
    if (nbase + 2 < nN) { begC = RFL(offs[nbase + 2]); endC = RFL(offs[nbase + 3]); }
    if (nbase + 3 < nN) { begD = RFL(offs[nbase + 3]); endD = RFL(offs[nbase + 4]); }

    float axA = 0.f, ayA = 0.f, axB = 0.f, ayB = 0.f;
    float axC = 0.f, ayC = 0.f, axD = 0.f, ayD = 0.f;
    int iA = begA, iB = begB, iC = begC, iD = begD;
    int4 a0, a1, b0, b1, c0, c1, d0, d1;
    bool lA = iA < endA, lB = iB < endB, lC = iC < endC, lD = iD < endD;
    if (lA) { a0 = *reinterpret_cast<const int4*>(eidx + RFL(iA));
              a1 = *reinterpret_cast<const int4*>(eidx + RFL(iA) + 4); }
    if (lB) { b0 = *reinterpret_cast<const int4*>(eidx + RFL(iB));
              b1 = *reinterpret_cast<const int4*>(eidx + RFL(iB) + 4); }
    if (lC) { c0 = *reinterpret_cast<const int4*>(eidx + RFL(iC));
              c1 = *reinterpret_cast<const int4*>(eidx + RFL(iC) + 4); }
    if (lD) { d0 = *reinterpret_cast<const int4*>(eidx + RFL(iD));
              d1 = *reinterpret_cast<const int4*>(eidx + RFL(iD) + 4); }

    while (lA | lB | lC | lD) {
        unsigned vA0, vA1, vA2, vA3, vA4, vA5, vA6, vA7;
        unsigned vB0, vB1, vB2, vB3, vB4, vB5, vB6, vB7;
        unsigned vC0, vC1, vC2, vC3, vC4, vC5, vC6, vC7;
        unsigned vD0, vD1, vD2, vD3, vD4, vD5, vD6, vD7;
        if (lA) { ISSUE8(vA, a0, a1) }
        if (lB) { ISSUE8(vB, b0, b1) }
        if (lC) { ISSUE8(vC, c0, c1) }
        if (lD) { ISSUE8(vD, d0, d1) }
        if (lA) { PREF(iA, endA, a0, a1) }
        if (lB) { PREF(iB, endB, b0, b1) }
        if (lC) { PREF(iC, endC, c0, c1) }
        if (lD) { PREF(iD, endD, d0, d1) }
        if (lA) { ACC8(vA, axA, ayA) iA += 8; }
        if (lB) { ACC8(vB, axB, ayB) iB += 8; }
        if (lC) { ACC8(vC, axC, ayC) iC += 8; }
        if (lD) { ACC8(vD, axD, ayD) iD += 8; }
        lA = iA < endA; lB = iB < endB; lC = iC < endC; lD = iD < endD;
    }

    tile[(wave * 4 + 0) * LROW + lane] = ((unsigned)f2bf(ayA) << 16) | (unsigned)f2bf(axA);
    tile[(wave * 4 + 1) * LROW + lane] = ((unsigned)f2bf(ayB) << 16) | (unsigned)f2bf(axB);
    tile[(wave * 4 + 2) * LROW + lane] = ((unsigned)f2bf(ayC) << 16) | (unsigned)f2bf(axC);
    tile[(wave * 4 + 3) * LROW + lane] = ((unsigned)f2bf(ayD) << 16) | (unsigned)f2bf(axD);
    __syncthreads();

    // ---- phase 2: [16 x 128] @ W  (2 col-tiles per wave) ----
    const int g = lane >> 4;       // k-group / C-row group
    const int cl = lane & 15;      // col-in-tile / A-row

    float di[4];
#pragma unroll
    for (int q = 0; q < 4; ++q)
        di[q] = dinv_in[min(blk16 + g * 4 + q, nN - 1)];

    f32x4 acc0 = (f32x4){0.f, 0.f, 0.f, 0.f};
    f32x4 acc1 = (f32x4){0.f, 0.f, 0.f, 0.f};
    const int col0 = wave * 16 + cl;
    const int col1 = (wave + 4) * 16 + cl;

#pragma unroll
    for (int s = 0; s < 4; ++s) {
        const bf16x8 a = *reinterpret_cast<const bf16x8*>(tile + cl * LROW + s * 16 + g * 4);
        const bf16x8 b0 = *reinterpret_cast<const bf16x8*>(wt + (size_t)col0 * IN_F + s * 32 + g * 8);
        const bf16x8 b1 = *reinterpret_cast<const bf16x8*>(wt + (size_t)col1 * IN_F + s * 32 + g * 8);
        acc0 = __builtin_amdgcn_mfma_f32_16x16x32_bf16(a, b0, acc0, 0, 0, 0);
        acc1 = __builtin_amdgcn_mfma_f32_16x16x32_bf16(a, b1, acc1, 0, 0, 0);
    }

    const float bv0 = bias[col0];
    const float bv1 = bias[col1];
#pragma unroll
    for (int q = 0; q < 4; ++q) {
        const int rr = blk16 + g * 4 + q;
        if (rr < nN) {
            out[(size_t)rr * IN_F + col0] = acc0[q] * di[q] + bv0;
            out[(size_t)rr * IN_F + col1] = acc1[q] * di[q] + bv1;
        }
    }
}

extern "C" void kernel_launch(void* const* d_in, const int* in_sizes, int n_in,
                              void* d_out, int out_size, void* d_ws, size_t ws_size,
                              hipStream_t stream) {
    const float* feat = (const float*)d_in[0];
    const int*   src  = (const int*)d_in[1];
    const int*   dst  = (const int*)d_in[2];
    const float* W    = (const float*)d_in[3];
    const float* bias = (const float*)d_in[4];
    float*       out  = (float*)d_out;

    const int nE = in_sizes[1];
    const int nN = in_sizes[0] / IN_F;
    const int nNs = nN + 1;                 // scan length (sentinel slot)
    const int nb = (nNs + 1023) / 1024;

    char* base = (char*)d_ws;
    int*            dstpart  = (int*)base;
    int*            srcpart  = (int*)(base + (size_t)HCD * nN * 4);
    unsigned short* h        = (unsigned short*)base;
    int*            eidx     = (int*)(base + (size_t)(HCD + HCS) * nN * 4);
    int*            eidx_end = eidx + nE + 8 * nN;  // capacity bound
    unsigned short* wt       = (unsigned short*)eidx_end;
    int*            cnt_pad  = (int*)(wt + 128 * 128);
    int*            creal    = cnt_pad + nNs + 4;
    float*          dinv_out = (float*)(creal + nN + 4);
    float*          dinv_in  = dinv_out + nN;
    int*            offs     = (int*)(dinv_in + nN);
    int*            partscan = offs + nNs + 4;

    k_hist    <<<HRH * (HCD + HCS), 256, 0, stream>>>(src, dst, dstpart, srcpart, nN, nE);
    k_merge   <<<(nNs + 255) / 256, 256, 0, stream>>>(dstpart, srcpart, cnt_pad, creal, dinv_out, dinv_in, nN);
    k_scan_blk<<<nb, 256, 0, stream>>>(cnt_pad, offs, partscan, nNs);
    k_scan_top<<<1, 256, 0, stream>>>(partscan, nb);
    k_scan_add<<<nb, 256, 0, stream>>>(offs, partscan, nNs);
    k_pad     <<<(nN + 255) / 256, 256, 0, stream>>>(offs, creal, eidx, nN);
    k_bin2    <<<HRB * HCD, 256, 0, stream>>>(src, dst, offs, dstpart, eidx, nN, nE);
    k_scale   <<<((nN + 1) * (IN_F / 4) + 255) / 256, 256, 0, stream>>>(feat, dinv_out, h, nN);
    k_wprep   <<<1, 256, 0, stream>>>(W, wt);
    k_gg      <<<(nN + 15) / 16, 256, 0, stream>>>(h, eidx, offs, wt, bias, dinv_in, out, nN);
}

// Round 13
// 119.425 us; speedup vs baseline: 1.0614x; 1.0614x over previous
//
#include <hip/hip_runtime.h>

#define IN_F 128
#define HRH 4            // hist node-ranges (LDS 50KB)
#define HCD 64           // dst chunks (= bin chunks, chunkoff table)
#define HCS 32           // src chunks (degree count only)
#define HRB 8            // bin node-ranges (LDS cursor 25KB)
#define HIST_RS 12544    // >= ceil(nN/HRH) for nN=50000
#define BIN_RS 6272      // >= ceil(nN/HRB)
#define LROW 68          // LDS tile row stride in uints (272B: conflict-free A-frag reads)

typedef __attribute__((ext_vector_type(8))) short bf16x8;
typedef __attribute__((ext_vector_type(4))) float f32x4;

static __device__ __forceinline__ unsigned short f2bf(float x) {
    unsigned u = __float_as_uint(x);
    unsigned r = (u + 0x7FFFu + ((u >> 16) & 1u)) >> 16;
    return (unsigned short)r;
}

#define RFL(x) __builtin_amdgcn_readfirstlane(x)

// ---------------- privatized histograms: dst (64 chunks) + src (32 chunks) ----
__global__ __launch_bounds__(256) void k_hist(const int* __restrict__ src,
                                              const int* __restrict__ dst,
                                              int* __restrict__ dstpart,
                                              int* __restrict__ srcpart,
                                              int* __restrict__ cursor,
                                              int nN, int nE) {
    __shared__ int h[HIST_RS];
    if (blockIdx.x == 0 && threadIdx.x == 0) *cursor = 0;  // for k_merge
    int bid = blockIdx.x;
    const int* key;
    int* part;
    int r, c, nch;
    if (bid < HRH * HCD) {
        key = dst; part = dstpart; nch = HCD;
        r = bid / HCD; c = bid % HCD;
    } else {
        bid -= HRH * HCD;
        key = src; part = srcpart; nch = HCS;
        r = bid / HCS; c = bid % HCS;
    }
    const int rs   = (nN + HRH - 1) / HRH;
    const int rbeg = r * rs;
    const int rsize = min(rs, nN - rbeg);
    if (rsize <= 0) return;

    for (int i = threadIdx.x; i < rsize; i += 256) h[i] = 0;
    __syncthreads();

    const int chunk = (nE + nch - 1) / nch;
    const int ebeg = c * chunk;
    const int eend = min(ebeg + chunk, nE);

    if ((ebeg & 3) == 0) {
        for (int i = ebeg + threadIdx.x * 4; i < eend; i += 256 * 4) {
            if (i + 3 < eend) {
                const int4 k4 = *reinterpret_cast<const int4*>(key + i);
                int a;
                a = k4.x - rbeg; if ((unsigned)a < (unsigned)rsize) atomicAdd(&h[a], 1);
                a = k4.y - rbeg; if ((unsigned)a < (unsigned)rsize) atomicAdd(&h[a], 1);
                a = k4.z - rbeg; if ((unsigned)a < (unsigned)rsize) atomicAdd(&h[a], 1);
                a = k4.w - rbeg; if ((unsigned)a < (unsigned)rsize) atomicAdd(&h[a], 1);
            } else {
                for (int j = i; j < eend; ++j) {
                    int a = key[j] - rbeg;
                    if ((unsigned)a < (unsigned)rsize) atomicAdd(&h[a], 1);
                }
            }
        }
    } else {
        for (int i = ebeg + threadIdx.x; i < eend; i += 256) {
            int a = key[i] - rbeg;
            if ((unsigned)a < (unsigned)rsize) atomicAdd(&h[a], 1);
        }
    }
    __syncthreads();

    int* pout = part + (size_t)c * nN + rbeg;
    for (int i = threadIdx.x; i < rsize; i += 256) pout[i] = h[i];
}

// ---------------- merge + in-kernel placement (replaces scan trio) ----------
// dst partials -> per-chunk prefixes (chunkoff); padded counts wave-scanned;
// one atomicAdd per wave on the global cursor assigns each node's bin base.
// Bins are disjoint but NOT node-ordered — consumers use offs[n] + cnt_pad[n].
__global__ __launch_bounds__(256) void k_merge(
    int* __restrict__ dstpart, const int* __restrict__ srcpart,
    int* __restrict__ cnt_pad, int* __restrict__ creal, int* __restrict__ offs,
    float* __restrict__ dinv_out, float* __restrict__ dinv_in,
    int* __restrict__ cursor, int nN) {
    const int n = blockIdx.x * blockDim.x + threadIdx.x;
    const int lane = threadIdx.x & 63;
    int s = 0, run = 0;
    if (n < nN) {
#pragma unroll 4
        for (int c = 0; c < HCS; ++c) s += srcpart[(size_t)c * nN + n];
#pragma unroll 4
        for (int c = 0; c < HCD; ++c) {
            const size_t idx = (size_t)c * nN + n;
            int v = dstpart[idx];
            dstpart[idx] = run;
            run += v;
        }
    }
    const int padded = (n < nN) ? ((run + 7) & ~7) : 0;
    // wave inclusive scan of padded
    int x = padded;
#pragma unroll
    for (int d = 1; d < 64; d <<= 1) {
        int y = __shfl_up(x, d);
        if (lane >= d) x += y;
    }
    const int total = __shfl(x, 63);
    int base = 0;
    if (lane == 63 && total > 0) base = atomicAdd(cursor, total);
    base = __shfl(base, 63);
    if (n < nN) {
        offs[n]     = base + x - padded;
        cnt_pad[n]  = padded;
        creal[n]    = run;
        dinv_out[n] = rsqrtf(fmaxf((float)s, 1.0f));
        dinv_in[n]  = rsqrtf(fmaxf((float)run, 1.0f));
    }
}

// ---------------- bucket edges by dst via LDS cursors (no global atomics) ----
__global__ __launch_bounds__(256) void k_bin2(const int* __restrict__ src,
                                              const int* __restrict__ dst,
                                              const int* __restrict__ offs,
                                              const int* __restrict__ chunkoff,
                                              int* __restrict__ eidx, int nN, int nE) {
    __shared__ int cur[BIN_RS];
    const int bid = blockIdx.x;
    const int r = bid / HCD;
    const int c = bid % HCD;
    const int rs = (nN + HRB - 1) / HRB;
    const int rbeg = r * rs;
    const int rsize = min(rs, nN - rbeg);
    if (rsize <= 0) return;

    for (int i = threadIdx.x; i < rsize; i += 256)
        cur[i] = offs[rbeg + i] + chunkoff[(size_t)c * nN + rbeg + i];
    __syncthreads();

    const int chunk = (nE + HCD - 1) / HCD;
    const int ebeg = c * chunk;
    const int eend = min(ebeg + chunk, nE);
    for (int i = ebeg + threadIdx.x * 4; i < eend; i += 256 * 4) {
        if (i + 3 < eend) {
            const int4 d4 = *reinterpret_cast<const int4*>(dst + i);
            int d;
            d = d4.x - rbeg; if ((unsigned)d < (unsigned)rsize) { int p = atomicAdd(&cur[d], 1); eidx[p] = src[i + 0]; }
            d = d4.y - rbeg; if ((unsigned)d < (unsigned)rsize) { int p = atomicAdd(&cur[d], 1); eidx[p] = src[i + 1]; }
            d = d4.z - rbeg; if ((unsigned)d < (unsigned)rsize) { int p = atomicAdd(&cur[d], 1); eidx[p] = src[i + 2]; }
            d = d4.w - rbeg; if ((unsigned)d < (unsigned)rsize) { int p = atomicAdd(&cur[d], 1); eidx[p] = src[i + 3]; }
        } else {
            for (int j = i; j < eend; ++j) {
                int d = dst[j] - rbeg;
                if ((unsigned)d < (unsigned)rsize) { int p = atomicAdd(&cur[d], 1); eidx[p] = src[j]; }
            }
        }
    }
}

// ---------------- fused prep: scale | pad | wprep (block-range dispatch) -----
__global__ __launch_bounds__(256) void k_prep(
    const float* __restrict__ feat, const float* __restrict__ dinv,
    unsigned short* __restrict__ h,
    const int* __restrict__ offs, const int* __restrict__ creal,
    const int* __restrict__ cnt_pad, int* __restrict__ eidx,
    const float* __restrict__ W, unsigned short* __restrict__ wt,
    int nN, int SB, int PB) {
    const int b = blockIdx.x;
    if (b < SB) {
        // h[n] = bf16(feat[n] * dinv_out[n]); row nN = zeros
        const int i = b * 256 + threadIdx.x;  // one thread = 4 elems
        if (i >= (nN + 1) * (IN_F / 4)) return;
        const int node = i >> 5;
        const int j = (i & 31) * 4;
        ushort4 o = make_ushort4(0, 0, 0, 0);
        if (node < nN) {
            const float s = dinv[node];
            const float4 v = *reinterpret_cast<const float4*>(feat + (size_t)node * IN_F + j);
            o.x = f2bf(v.x * s);
            o.y = f2bf(v.y * s);
            o.z = f2bf(v.z * s);
            o.w = f2bf(v.w * s);
        }
        *reinterpret_cast<ushort4*>(h + (size_t)node * IN_F + j) = o;
    } else if (b < SB + PB) {
        // pad slots -> zero-row index nN
        const int n = (b - SB) * 256 + threadIdx.x;
        if (n >= nN) return;
        const int base = offs[n];
        const int st = base + creal[n];
        const int e  = base + cnt_pad[n];
        for (int i = st; i < e; ++i) eidx[i] = nN;
    } else {
        // wt[col][k] = bf16(W[k][col]) — 16384 elems over 64 blocks
        const int t = (b - SB - PB) * 256 + threadIdx.x;
        if (t >= 128 * 128) return;
        const int col = t >> 7;
        const int k = t & 127;
        wt[col * 128 + k] = f2bf(W[k * 128 + col]);
    }
}

// ---------------- fused gather + GEMM, scalar-index 2-row-interleaved gather ---
#define ISSUE8(vv, a0, a1)                                                        \
    vv##0 = *reinterpret_cast<const unsigned*>(h + (size_t)RFL(a0.x) * IN_F + lo); \
    vv##1 = *reinterpret_cast<const unsigned*>(h + (size_t)RFL(a0.y) * IN_F + lo); \
    vv##2 = *reinterpret_cast<const unsigned*>(h + (size_t)RFL(a0.z) * IN_F + lo); \
    vv##3 = *reinterpret_cast<const unsigned*>(h + (size_t)RFL(a0.w) * IN_F + lo); \
    vv##4 = *reinterpret_cast<const unsigned*>(h + (size_t)RFL(a1.x) * IN_F + lo); \
    vv##5 = *reinterpret_cast<const unsigned*>(h + (size_t)RFL(a1.y) * IN_F + lo); \
    vv##6 = *reinterpret_cast<const unsigned*>(h + (size_t)RFL(a1.z) * IN_F + lo); \
    vv##7 = *reinterpret_cast<const unsigned*>(h + (size_t)RFL(a1.w) * IN_F + lo);

#define ACC8(vv, ax, ay)                                                            \
    ax += __uint_as_float(vv##0 << 16); ay += __uint_as_float(vv##0 & 0xFFFF0000u); \
    ax += __uint_as_float(vv##1 << 16); ay += __uint_as_float(vv##1 & 0xFFFF0000u); \
    ax += __uint_as_float(vv##2 << 16); ay += __uint_as_float(vv##2 & 0xFFFF0000u); \
    ax += __uint_as_float(vv##3 << 16); ay += __uint_as_float(vv##3 & 0xFFFF0000u); \
    ax += __uint_as_float(vv##4 << 16); ay += __uint_as_float(vv##4 & 0xFFFF0000u); \
    ax += __uint_as_float(vv##5 << 16); ay += __uint_as_float(vv##5 & 0xFFFF0000u); \
    ax += __uint_as_float(vv##6 << 16); ay += __uint_as_float(vv##6 & 0xFFFF0000u); \
    ax += __uint_as_float(vv##7 << 16); ay += __uint_as_float(vv##7 & 0xFFFF0000u);

__global__ __launch_bounds__(256) void k_gg(
    const unsigned short* __restrict__ h, const int* __restrict__ eidx,
    const int* __restrict__ offs, const int* __restrict__ cnt_pad,
    const unsigned short* __restrict__ wt,
    const float* __restrict__ bias, const float* __restrict__ dinv_in,
    float* __restrict__ out, int nN) {
    __shared__ unsigned tile[16 * LROW];
    const int lane = threadIdx.x & 63;
    const int wave = threadIdx.x >> 6;
    const int blk16 = blockIdx.x * 16;
    const size_t lo = (size_t)(lane * 2);
    const int nbase = blk16 + wave * 4;

#pragma unroll
    for (int p = 0; p < 2; ++p) {
        const int rA = nbase + 2 * p;
        const int rB = rA + 1;
        int begA = 0, endA = 0, begB = 0, endB = 0;
        if (rA < nN) { begA = RFL(offs[rA]); endA = begA + RFL(cnt_pad[rA]); }
        if (rB < nN) { begB = RFL(offs[rB]); endB = begB + RFL(cnt_pad[rB]); }

        float axA = 0.f, ayA = 0.f, axB = 0.f, ayB = 0.f;
        int iA = begA, iB = begB;
        int4 a0, a1, b0, b1;
        bool lA = iA < endA, lB = iB < endB;
        if (lA) { a0 = *reinterpret_cast<const int4*>(eidx + RFL(iA));
                  a1 = *reinterpret_cast<const int4*>(eidx + RFL(iA) + 4); }
        if (lB) { b0 = *reinterpret_cast<const int4*>(eidx + RFL(iB));
                  b1 = *reinterpret_cast<const int4*>(eidx + RFL(iB) + 4); }

        while (lA | lB) {
            unsigned vA0, vA1, vA2, vA3, vA4, vA5, vA6, vA7;
            unsigned vB0, vB1, vB2, vB3, vB4, vB5, vB6, vB7;
            if (lA) { ISSUE8(vA, a0, a1) }
            if (lB) { ISSUE8(vB, b0, b1) }
            // prefetch next idx batches while h-loads are in flight
            if (iA + 8 < endA) { a0 = *reinterpret_cast<const int4*>(eidx + RFL(iA) + 8);
                                 a1 = *reinterpret_cast<const int4*>(eidx + RFL(iA) + 12); }
            if (iB + 8 < endB) { b0 = *reinterpret_cast<const int4*>(eidx + RFL(iB) + 8);
                                 b1 = *reinterpret_cast<const int4*>(eidx + RFL(iB) + 12); }
            if (lA) { ACC8(vA, axA, ayA) iA += 8; }
            if (lB) { ACC8(vB, axB, ayB) iB += 8; }
            lA = iA < endA; lB = iB < endB;
        }

        tile[(wave * 4 + 2 * p + 0) * LROW + lane] = ((unsigned)f2bf(ayA) << 16) | (unsigned)f2bf(axA);
        tile[(wave * 4 + 2 * p + 1) * LROW + lane] = ((unsigned)f2bf(ayB) << 16) | (unsigned)f2bf(axB);
    }
    __syncthreads();

    // ---- phase 2: [16 x 128] @ W  (2 col-tiles per wave) ----
    const int g = lane >> 4;       // k-group / C-row group
    const int cl = lane & 15;      // col-in-tile / A-row

    float di[4];
#pragma unroll
    for (int q = 0; q < 4; ++q)
        di[q] = dinv_in[min(blk16 + g * 4 + q, nN - 1)];

    f32x4 acc0 = (f32x4){0.f, 0.f, 0.f, 0.f};
    f32x4 acc1 = (f32x4){0.f, 0.f, 0.f, 0.f};
    const int col0 = wave * 16 + cl;
    const int col1 = (wave + 4) * 16 + cl;

#pragma unroll
    for (int s = 0; s < 4; ++s) {
        const bf16x8 a = *reinterpret_cast<const bf16x8*>(tile + cl * LROW + s * 16 + g * 4);
        const bf16x8 b0 = *reinterpret_cast<const bf16x8*>(wt + (size_t)col0 * IN_F + s * 32 + g * 8);
        const bf16x8 b1 = *reinterpret_cast<const bf16x8*>(wt + (size_t)col1 * IN_F + s * 32 + g * 8);
        acc0 = __builtin_amdgcn_mfma_f32_16x16x32_bf16(a, b0, acc0, 0, 0, 0);
        acc1 = __builtin_amdgcn_mfma_f32_16x16x32_bf16(a, b1, acc1, 0, 0, 0);
    }

    const float bv0 = bias[col0];
    const float bv1 = bias[col1];
#pragma unroll
    for (int q = 0; q < 4; ++q) {
        const int rr = blk16 + g * 4 + q;
        if (rr < nN) {
            out[(size_t)rr * IN_F + col0] = acc0[q] * di[q] + bv0;
            out[(size_t)rr * IN_F + col1] = acc1[q] * di[q] + bv1;
        }
    }
}

extern "C" void kernel_launch(void* const* d_in, const int* in_sizes, int n_in,
                              void* d_out, int out_size, void* d_ws, size_t ws_size,
                              hipStream_t stream) {
    const float* feat = (const float*)d_in[0];
    const int*   src  = (const int*)d_in[1];
    const int*   dst  = (const int*)d_in[2];
    const float* W    = (const float*)d_in[3];
    const float* bias = (const float*)d_in[4];
    float*       out  = (float*)d_out;

    const int nE = in_sizes[1];
    const int nN = in_sizes[0] / IN_F;

    // workspace (aliased, ~25MB):
    //  [0, 12.8M)          dstpart [HCD][nN] (hist->merge->bin2) | then h bf16 (nN+1 rows, prep->gg)
    //  [12.8M, 19.2M)      srcpart [HCS][nN] (hist->merge)
    //  [19.2M, 24.0M)      eidx padded (bin2/prep->gg)
    //  tail: wt, cnt_pad, creal, dinv_out, dinv_in, offs, cursor
    char* base = (char*)d_ws;
    int*            dstpart  = (int*)base;
    int*            srcpart  = (int*)(base + (size_t)HCD * nN * 4);
    unsigned short* h        = (unsigned short*)base;
    int*            eidx     = (int*)(base + (size_t)(HCD + HCS) * nN * 4);
    int*            eidx_end = eidx + nE + 8 * nN;  // capacity bound
    unsigned short* wt       = (unsigned short*)eidx_end;
    int*            cnt_pad  = (int*)(wt + 128 * 128);
    int*            creal    = cnt_pad + nN + 4;
    float*          dinv_out = (float*)(creal + nN + 4);
    float*          dinv_in  = dinv_out + nN;
    int*            offs     = (int*)(dinv_in + nN);
    int*            cursor   = offs + nN + 4;

    const int SB = ((nN + 1) * (IN_F / 4) + 255) / 256;  // scale blocks
    const int PB = (nN + 255) / 256;                     // pad blocks
    const int WB = (128 * 128 + 255) / 256;              // wprep blocks

    k_hist <<<HRH * (HCD + HCS), 256, 0, stream>>>(src, dst, dstpart, srcpart, cursor, nN, nE);
    k_merge<<<(nN + 255) / 256, 256, 0, stream>>>(dstpart, srcpart, cnt_pad, creal, offs,
                                                  dinv_out, dinv_in, cursor, nN);
    k_bin2 <<<HRB * HCD, 256, 0, stream>>>(src, dst, offs, dstpart, eidx, nN, nE);
    k_prep <<<SB + PB + WB, 256, 0, stream>>>(feat, dinv_out, h, offs, creal, cnt_pad,
                                              eidx, W, wt, nN, SB, PB);
    k_gg   <<<(nN + 15) / 16, 256, 0, stream>>>(h, eidx, offs, cnt_pad, wt, bias, dinv_in, out, nN);
}

// Round 14
// 115.963 us; speedup vs baseline: 1.0931x; 1.0299x over previous
//
#include <hip/hip_runtime.h>

#define IN_F 128
#define HRH 4            // hist node-ranges (LDS 50KB)
#define HCD 64           // dst chunks (= bin chunks, chunkoff table)
#define HCS 32           // src chunks (degree count only)
#define HRB 8            // bin node-ranges (LDS cursor 25KB)
#define HIST_RS 12544    // >= ceil(nN/HRH) for nN=50000
#define BIN_RS 6272      // >= ceil(nN/HRB)
#define LROW 68          // LDS tile row stride in uints (272B: conflict-free A-frag reads)

typedef __attribute__((ext_vector_type(8))) short bf16x8;
typedef __attribute__((ext_vector_type(4))) float f32x4;

static __device__ __forceinline__ unsigned short f2bf(float x) {
    unsigned u = __float_as_uint(x);
    unsigned r = (u + 0x7FFFu + ((u >> 16) & 1u)) >> 16;
    return (unsigned short)r;
}

#define RFL(x) __builtin_amdgcn_readfirstlane(x)

// ---------------- privatized histograms: dst (64 chunks) + src (32 chunks) ----
__global__ __launch_bounds__(256) void k_hist(const int* __restrict__ src,
                                              const int* __restrict__ dst,
                                              int* __restrict__ dstpart,
                                              int* __restrict__ srcpart,
                                              int* __restrict__ cursor,
                                              int nN, int nE) {
    __shared__ int h[HIST_RS];
    if (blockIdx.x == 0 && threadIdx.x == 0) *cursor = 0;  // for k_merge
    int bid = blockIdx.x;
    const int* key;
    int* part;
    int r, c, nch;
    if (bid < HRH * HCD) {
        key = dst; part = dstpart; nch = HCD;
        r = bid / HCD; c = bid % HCD;
    } else {
        bid -= HRH * HCD;
        key = src; part = srcpart; nch = HCS;
        r = bid / HCS; c = bid % HCS;
    }
    const int rs   = (nN + HRH - 1) / HRH;
    const int rbeg = r * rs;
    const int rsize = min(rs, nN - rbeg);
    if (rsize <= 0) return;

    for (int i = threadIdx.x; i < rsize; i += 256) h[i] = 0;
    __syncthreads();

    const int chunk = (nE + nch - 1) / nch;
    const int ebeg = c * chunk;
    const int eend = min(ebeg + chunk, nE);

    if ((ebeg & 3) == 0) {
        for (int i = ebeg + threadIdx.x * 4; i < eend; i += 256 * 4) {
            if (i + 3 < eend) {
                const int4 k4 = *reinterpret_cast<const int4*>(key + i);
                int a;
                a = k4.x - rbeg; if ((unsigned)a < (unsigned)rsize) atomicAdd(&h[a], 1);
                a = k4.y - rbeg; if ((unsigned)a < (unsigned)rsize) atomicAdd(&h[a], 1);
                a = k4.z - rbeg; if ((unsigned)a < (unsigned)rsize) atomicAdd(&h[a], 1);
                a = k4.w - rbeg; if ((unsigned)a < (unsigned)rsize) atomicAdd(&h[a], 1);
            } else {
                for (int j = i; j < eend; ++j) {
                    int a = key[j] - rbeg;
                    if ((unsigned)a < (unsigned)rsize) atomicAdd(&h[a], 1);
                }
            }
        }
    } else {
        for (int i = ebeg + threadIdx.x; i < eend; i += 256) {
            int a = key[i] - rbeg;
            if ((unsigned)a < (unsigned)rsize) atomicAdd(&h[a], 1);
        }
    }
    __syncthreads();

    int* pout = part + (size_t)c * nN + rbeg;
    for (int i = threadIdx.x; i < rsize; i += 256) pout[i] = h[i];
}

// ---------------- merge + in-kernel placement (wave-scan + cursor atomic) ----
__global__ __launch_bounds__(256) void k_merge(
    int* __restrict__ dstpart, const int* __restrict__ srcpart,
    int* __restrict__ cnt_pad, int* __restrict__ creal, int* __restrict__ offs,
    float* __restrict__ dinv_out, float* __restrict__ dinv_in,
    int* __restrict__ cursor, int nN) {
    const int n = blockIdx.x * blockDim.x + threadIdx.x;
    const int lane = threadIdx.x & 63;
    int s = 0, run = 0;
    if (n < nN) {
#pragma unroll 4
        for (int c = 0; c < HCS; ++c) s += srcpart[(size_t)c * nN + n];
#pragma unroll 4
        for (int c = 0; c < HCD; ++c) {
            const size_t idx = (size_t)c * nN + n;
            int v = dstpart[idx];
            dstpart[idx] = run;
            run += v;
        }
    }
    const int padded = (n < nN) ? ((run + 7) & ~7) : 0;
    int x = padded;
#pragma unroll
    for (int d = 1; d < 64; d <<= 1) {
        int y = __shfl_up(x, d);
        if (lane >= d) x += y;
    }
    const int total = __shfl(x, 63);
    int base = 0;
    if (lane == 63 && total > 0) base = atomicAdd(cursor, total);
    base = __shfl(base, 63);
    if (n < nN) {
        offs[n]     = base + x - padded;
        cnt_pad[n]  = padded;
        creal[n]    = run;
        dinv_out[n] = rsqrtf(fmaxf((float)s, 1.0f));
        dinv_in[n]  = rsqrtf(fmaxf((float)run, 1.0f));
    }
}

// ---------------- bucket edges by dst via LDS cursors (no global atomics) ----
__global__ __launch_bounds__(256) void k_bin2(const int* __restrict__ src,
                                              const int* __restrict__ dst,
                                              const int* __restrict__ offs,
                                              const int* __restrict__ chunkoff,
                                              int* __restrict__ eidx, int nN, int nE) {
    __shared__ int cur[BIN_RS];
    const int bid = blockIdx.x;
    const int r = bid / HCD;
    const int c = bid % HCD;
    const int rs = (nN + HRB - 1) / HRB;
    const int rbeg = r * rs;
    const int rsize = min(rs, nN - rbeg);
    if (rsize <= 0) return;

    for (int i = threadIdx.x; i < rsize; i += 256)
        cur[i] = offs[rbeg + i] + chunkoff[(size_t)c * nN + rbeg + i];
    __syncthreads();

    const int chunk = (nE + HCD - 1) / HCD;
    const int ebeg = c * chunk;
    const int eend = min(ebeg + chunk, nE);
    for (int i = ebeg + threadIdx.x * 4; i < eend; i += 256 * 4) {
        if (i + 3 < eend) {
            const int4 d4 = *reinterpret_cast<const int4*>(dst + i);
            int d;
            d = d4.x - rbeg; if ((unsigned)d < (unsigned)rsize) { int p = atomicAdd(&cur[d], 1); eidx[p] = src[i + 0]; }
            d = d4.y - rbeg; if ((unsigned)d < (unsigned)rsize) { int p = atomicAdd(&cur[d], 1); eidx[p] = src[i + 1]; }
            d = d4.z - rbeg; if ((unsigned)d < (unsigned)rsize) { int p = atomicAdd(&cur[d], 1); eidx[p] = src[i + 2]; }
            d = d4.w - rbeg; if ((unsigned)d < (unsigned)rsize) { int p = atomicAdd(&cur[d], 1); eidx[p] = src[i + 3]; }
        } else {
            for (int j = i; j < eend; ++j) {
                int d = dst[j] - rbeg;
                if ((unsigned)d < (unsigned)rsize) { int p = atomicAdd(&cur[d], 1); eidx[p] = src[j]; }
            }
        }
    }
}

// ---------------- fused prep: scale | pad | wprep (block-range dispatch) -----
__global__ __launch_bounds__(256) void k_prep(
    const float* __restrict__ feat, const float* __restrict__ dinv,
    unsigned short* __restrict__ h,
    const int* __restrict__ offs, const int* __restrict__ creal,
    const int* __restrict__ cnt_pad, int* __restrict__ eidx,
    const float* __restrict__ W, unsigned short* __restrict__ wt,
    int nN, int SB, int PB) {
    const int b = blockIdx.x;
    if (b < SB) {
        const int i = b * 256 + threadIdx.x;  // one thread = 4 elems
        if (i >= (nN + 1) * (IN_F / 4)) return;
        const int node = i >> 5;
        const int j = (i & 31) * 4;
        ushort4 o = make_ushort4(0, 0, 0, 0);
        if (node < nN) {
            const float s = dinv[node];
            const float4 v = *reinterpret_cast<const float4*>(feat + (size_t)node * IN_F + j);
            o.x = f2bf(v.x * s);
            o.y = f2bf(v.y * s);
            o.z = f2bf(v.z * s);
            o.w = f2bf(v.w * s);
        }
        *reinterpret_cast<ushort4*>(h + (size_t)node * IN_F + j) = o;
    } else if (b < SB + PB) {
        const int n = (b - SB) * 256 + threadIdx.x;
        if (n >= nN) return;
        const int base = offs[n];
        const int st = base + creal[n];
        const int e  = base + cnt_pad[n];
        for (int i = st; i < e; ++i) eidx[i] = nN;
    } else {
        const int t = (b - SB - PB) * 256 + threadIdx.x;
        if (t >= 128 * 128) return;
        const int col = t >> 7;
        const int k = t & 127;
        wt[col * 128 + k] = f2bf(W[k * 128 + col]);
    }
}

// ---------------- fused gather + GEMM: 8 waves/block, 2 nodes per wave --------
// Each wave gathers exactly TWO nodes (one 2-row interleaved pass — the serial
// p-loop of R13 is gone; 2x waves carry the same node workload). Phase 2: each
// wave computes one 16-col MFMA tile of the 16x128 output block.
#define ISSUE8(vv, a0, a1)                                                        \
    vv##0 = *reinterpret_cast<const unsigned*>(h + (size_t)RFL(a0.x) * IN_F + lo); \
    vv##1 = *reinterpret_cast<const unsigned*>(h + (size_t)RFL(a0.y) * IN_F + lo); \
    vv##2 = *reinterpret_cast<const unsigned*>(h + (size_t)RFL(a0.z) * IN_F + lo); \
    vv##3 = *reinterpret_cast<const unsigned*>(h + (size_t)RFL(a0.w) * IN_F + lo); \
    vv##4 = *reinterpret_cast<const unsigned*>(h + (size_t)RFL(a1.x) * IN_F + lo); \
    vv##5 = *reinterpret_cast<const unsigned*>(h + (size_t)RFL(a1.y) * IN_F + lo); \
    vv##6 = *reinterpret_cast<const unsigned*>(h + (size_t)RFL(a1.z) * IN_F + lo); \
    vv##7 = *reinterpret_cast<const unsigned*>(h + (size_t)RFL(a1.w) * IN_F + lo);

#define ACC8(vv, ax, ay)                                                            \
    ax += __uint_as_float(vv##0 << 16); ay += __uint_as_float(vv##0 & 0xFFFF0000u); \
    ax += __uint_as_float(vv##1 << 16); ay += __uint_as_float(vv##1 & 0xFFFF0000u); \
    ax += __uint_as_float(vv##2 << 16); ay += __uint_as_float(vv##2 & 0xFFFF0000u); \
    ax += __uint_as_float(vv##3 << 16); ay += __uint_as_float(vv##3 & 0xFFFF0000u); \
    ax += __uint_as_float(vv##4 << 16); ay += __uint_as_float(vv##4 & 0xFFFF0000u); \
    ax += __uint_as_float(vv##5 << 16); ay += __uint_as_float(vv##5 & 0xFFFF0000u); \
    ax += __uint_as_float(vv##6 << 16); ay += __uint_as_float(vv##6 & 0xFFFF0000u); \
    ax += __uint_as_float(vv##7 << 16); ay += __uint_as_float(vv##7 & 0xFFFF0000u);

__global__ __launch_bounds__(512) void k_gg(
    const unsigned short* __restrict__ h, const int* __restrict__ eidx,
    const int* __restrict__ offs, const int* __restrict__ cnt_pad,
    const unsigned short* __restrict__ wt,
    const float* __restrict__ bias, const float* __restrict__ dinv_in,
    float* __restrict__ out, int nN) {
    __shared__ unsigned tile[16 * LROW];
    const int lane = threadIdx.x & 63;
    const int wave = threadIdx.x >> 6;      // 0..7
    const int blk16 = blockIdx.x * 16;
    const size_t lo = (size_t)(lane * 2);

    // ---- phase 1: this wave gathers nodes rA = blk16+2*wave, rB = rA+1 ----
    const int rA = blk16 + wave * 2;
    const int rB = rA + 1;
    int begA = 0, endA = 0, begB = 0, endB = 0;
    if (rA < nN) { begA = RFL(offs[rA]); endA = begA + RFL(cnt_pad[rA]); }
    if (rB < nN) { begB = RFL(offs[rB]); endB = begB + RFL(cnt_pad[rB]); }

    float axA = 0.f, ayA = 0.f, axB = 0.f, ayB = 0.f;
    int iA = begA, iB = begB;
    int4 a0, a1, b0, b1;
    bool lA = iA < endA, lB = iB < endB;
    if (lA) { a0 = *reinterpret_cast<const int4*>(eidx + RFL(iA));
              a1 = *reinterpret_cast<const int4*>(eidx + RFL(iA) + 4); }
    if (lB) { b0 = *reinterpret_cast<const int4*>(eidx + RFL(iB));
              b1 = *reinterpret_cast<const int4*>(eidx + RFL(iB) + 4); }

    while (lA | lB) {
        unsigned vA0, vA1, vA2, vA3, vA4, vA5, vA6, vA7;
        unsigned vB0, vB1, vB2, vB3, vB4, vB5, vB6, vB7;
        if (lA) { ISSUE8(vA, a0, a1) }
        if (lB) { ISSUE8(vB, b0, b1) }
        if (iA + 8 < endA) { a0 = *reinterpret_cast<const int4*>(eidx + RFL(iA) + 8);
                             a1 = *reinterpret_cast<const int4*>(eidx + RFL(iA) + 12); }
        if (iB + 8 < endB) { b0 = *reinterpret_cast<const int4*>(eidx + RFL(iB) + 8);
                             b1 = *reinterpret_cast<const int4*>(eidx + RFL(iB) + 12); }
        if (lA) { ACC8(vA, axA, ayA) iA += 8; }
        if (lB) { ACC8(vB, axB, ayB) iB += 8; }
        lA = iA < endA; lB = iB < endB;
    }

    tile[(wave * 2 + 0) * LROW + lane] = ((unsigned)f2bf(ayA) << 16) | (unsigned)f2bf(axA);
    tile[(wave * 2 + 1) * LROW + lane] = ((unsigned)f2bf(ayB) << 16) | (unsigned)f2bf(axB);
    __syncthreads();

    // ---- phase 2: [16 x 128] @ W — each wave computes one 16-col tile ----
    const int g = lane >> 4;       // k-group / C-row group
    const int cl = lane & 15;      // col-in-tile / A-row

    float di[4];
#pragma unroll
    for (int q = 0; q < 4; ++q)
        di[q] = dinv_in[min(blk16 + g * 4 + q, nN - 1)];

    f32x4 acc = (f32x4){0.f, 0.f, 0.f, 0.f};
    const int col = wave * 16 + cl;

#pragma unroll
    for (int s = 0; s < 4; ++s) {
        const bf16x8 a = *reinterpret_cast<const bf16x8*>(tile + cl * LROW + s * 16 + g * 4);
        const bf16x8 b = *reinterpret_cast<const bf16x8*>(wt + (size_t)col * IN_F + s * 32 + g * 8);
        acc = __builtin_amdgcn_mfma_f32_16x16x32_bf16(a, b, acc, 0, 0, 0);
    }

    const float bv = bias[col];
#pragma unroll
    for (int q = 0; q < 4; ++q) {
        const int rr = blk16 + g * 4 + q;
        if (rr < nN)
            out[(size_t)rr * IN_F + col] = acc[q] * di[q] + bv;
    }
}

extern "C" void kernel_launch(void* const* d_in, const int* in_sizes, int n_in,
                              void* d_out, int out_size, void* d_ws, size_t ws_size,
                              hipStream_t stream) {
    const float* feat = (const float*)d_in[0];
    const int*   src  = (const int*)d_in[1];
    const int*   dst  = (const int*)d_in[2];
    const float* W    = (const float*)d_in[3];
    const float* bias = (const float*)d_in[4];
    float*       out  = (float*)d_out;

    const int nE = in_sizes[1];
    const int nN = in_sizes[0] / IN_F;

    char* base = (char*)d_ws;
    int*            dstpart  = (int*)base;
    int*            srcpart  = (int*)(base + (size_t)HCD * nN * 4);
    unsigned short* h        = (unsigned short*)base;
    int*            eidx     = (int*)(base + (size_t)(HCD + HCS) * nN * 4);
    int*            eidx_end = eidx + nE + 8 * nN;  // capacity bound
    unsigned short* wt       = (unsigned short*)eidx_end;
    int*            cnt_pad  = (int*)(wt + 128 * 128);
    int*            creal    = cnt_pad + nN + 4;
    float*          dinv_out = (float*)(creal + nN + 4);
    float*          dinv_in  = dinv_out + nN;
    int*            offs     = (int*)(dinv_in + nN);
    int*            cursor   = offs + nN + 4;

    const int SB = ((nN + 1) * (IN_F / 4) + 255) / 256;  // scale blocks
    const int PB = (nN + 255) / 256;                     // pad blocks
    const int WB = (128 * 128 + 255) / 256;              // wprep blocks

    k_hist <<<HRH * (HCD + HCS), 256, 0, stream>>>(src, dst, dstpart, srcpart, cursor, nN, nE);
    k_merge<<<(nN + 255) / 256, 256, 0, stream>>>(dstpart, srcpart, cnt_pad, creal, offs,
                                                  dinv_out, dinv_in, cursor, nN);
    k_bin2 <<<HRB * HCD, 256, 0, stream>>>(src, dst, offs, dstpart, eidx, nN, nE);
    k_prep <<<SB + PB + WB, 256, 0, stream>>>(feat, dinv_out, h, offs, creal, cnt_pad,
                                              eidx, W, wt, nN, SB, PB);
    k_gg   <<<(nN + 15) / 16, 512, 0, stream>>>(h, eidx, offs, cnt_pad, wt, bias, dinv_in, out, nN);
}